// Round 8
// baseline (395.175 us; speedup 1.0000x reference)
//
#include <hip/hip_runtime.h>
#include <hip/hip_cooperative_groups.h>

namespace cg = cooperative_groups;

#define DIM 6
#define NSEG 65535
#define CH 64            // segments per wave-chunk
#define NCHUNK 1024      // 256 blocks x 4 waves

// Padded partial-signature layout, stride in floats.
// 16B-aligned sections: L1@0(6), L2@8(36), L3@48(216), L4@264(1296)
#define PSTRIDE 1568
#define PL1 0
#define PL2 8
#define PL3 48
#define PL4 264

// ---- device-scope (cross-XCD-safe) scalar access --------------------------
__device__ __forceinline__ void gstore(float* p, float v) {
    __hip_atomic_store(p, v, __ATOMIC_RELAXED, __HIP_MEMORY_SCOPE_AGENT);
}
__device__ __forceinline__ float gload(const float* p) {
    return __hip_atomic_load((float*)p, __ATOMIC_RELAXED, __HIP_MEMORY_SCOPE_AGENT);
}

// ---- register-resident Chen accumulate: Acc = Acc (x) U  (U in LDS) -------
// Lane ab owns T4 row ab (36), T3 row ab (6), T2[ab], S1[a].  All register
// arrays const-indexed in fully unrolled loops; lane-dependent operands are
// per-lane-addressed LDS reads.
__device__ __forceinline__ void acc_chen(const float* __restrict__ Us,
                                         int ab, int a, int b,
                                         float* r4, float* r3,
                                         float& r2, float& s1) {
    float b1[6];
#pragma unroll
    for (int d = 0; d < 6; ++d) b1[d] = Us[PL1 + d];
    float b2[36];
#pragma unroll
    for (int i = 0; i < 9; ++i) {
        float4 q = *(const float4*)(Us + PL2 + 4 * i);
        b2[4 * i] = q.x; b2[4 * i + 1] = q.y;
        b2[4 * i + 2] = q.z; b2[4 * i + 3] = q.w;
    }
    float b1a = Us[PL1 + a];
    float b1b = Us[PL1 + b];
    float b2ab = Us[PL2 + ab];
    float b2rb[6];
    {
        const float* p = Us + PL2 + b * 6;
#pragma unroll
        for (int i = 0; i < 3; ++i) {
            float2 q = *(const float2*)(p + 2 * i);
            b2rb[2 * i] = q.x; b2rb[2 * i + 1] = q.y;
        }
    }
    float b3ab[6];
    {
        const float* p = Us + PL3 + ab * 6;
#pragma unroll
        for (int i = 0; i < 3; ++i) {
            float2 q = *(const float2*)(p + 2 * i);
            b3ab[2 * i] = q.x; b3ab[2 * i + 1] = q.y;
        }
    }
    float b3b[36];                     // B3 block row b
    {
        const float* p = Us + PL3 + b * 36;
#pragma unroll
        for (int i = 0; i < 9; ++i) {
            float4 q = *(const float4*)(p + 4 * i);
            b3b[4 * i] = q.x; b3b[4 * i + 1] = q.y;
            b3b[4 * i + 2] = q.z; b3b[4 * i + 3] = q.w;
        }
    }
    float b4[36];                      // B4 row ab
    {
        const float* p = Us + PL4 + ab * 36;
#pragma unroll
        for (int i = 0; i < 9; ++i) {
            float4 q = *(const float4*)(p + 4 * i);
            b4[4 * i] = q.x; b4[4 * i + 1] = q.y;
            b4[4 * i + 2] = q.z; b4[4 * i + 3] = q.w;
        }
    }
    // T4 (old r3, r2, s1)
#pragma unroll
    for (int cc = 0; cc < 6; ++cc)
#pragma unroll
        for (int d = 0; d < 6; ++d) {
            const int cd = cc * 6 + d;
            float v = r4[cd] + b4[cd];
            v = fmaf(r3[cc], b1[d], v);
            v = fmaf(r2, b2[cd], v);
            r4[cd] = fmaf(s1, b3b[cd], v);
        }
    // T3 (old r2, s1)
#pragma unroll
    for (int cc = 0; cc < 6; ++cc) {
        float v = r3[cc] + b3ab[cc];
        v = fmaf(r2, b1[cc], v);
        r3[cc] = fmaf(s1, b2rb[cc], v);
    }
    // T2, T1 (old s1)
    r2 = fmaf(s1, b1b, r2 + b2ab);
    s1 += b1a;
}

// load accumulator from padded signature in LDS
__device__ __forceinline__ void acc_load(const float* __restrict__ P,
                                         int ab, int a,
                                         float* r4, float* r3,
                                         float& r2, float& s1) {
    s1 = P[PL1 + a];
    r2 = P[PL2 + ab];
    const float* p3 = P + PL3 + ab * 6;
#pragma unroll
    for (int i = 0; i < 3; ++i) {
        float2 q = *(const float2*)(p3 + 2 * i);
        r3[2 * i] = q.x; r3[2 * i + 1] = q.y;
    }
    const float* p4 = P + PL4 + ab * 36;
#pragma unroll
    for (int i = 0; i < 9; ++i) {
        float4 q = *(const float4*)(p4 + 4 * i);
        r4[4 * i] = q.x; r4[4 * i + 1] = q.y;
        r4[4 * i + 2] = q.z; r4[4 * i + 3] = q.w;
    }
}

// store accumulator to padded signature in global (device-scope scalars)
__device__ __forceinline__ void acc_store_agent(float* __restrict__ P,
                                                int ab, int a, int b,
                                                const float* r4, const float* r3,
                                                float r2, float s1) {
    if (a == b) gstore(&P[PL1 + a], s1);
    gstore(&P[PL2 + ab], r2);
    float* p3 = P + PL3 + ab * 6;
#pragma unroll
    for (int i = 0; i < 6; ++i) gstore(&p3[i], r3[i]);
    float* p4 = P + PL4 + ab * 36;
#pragma unroll
    for (int i = 0; i < 36; ++i) gstore(&p4[i], r4[i]);
}

// ---- one fused cooperative kernel -----------------------------------------
__global__ __launch_bounds__(256, 1) void sig_all(const float* __restrict__ x,
                                                  float* __restrict__ out,
                                                  float* __restrict__ ws0,
                                                  float* __restrict__ ws1,
                                                  float* __restrict__ ws2,
                                                  float* __restrict__ ws3) {
    __shared__ __align__(16) float lds[8 * PSTRIDE];   // 50.2 KB
    cg::grid_group grid = cg::this_grid();
    const int t = threadIdx.x;
    const int w = t >> 6, lane = t & 63;
    const int ab = (lane < 36) ? lane : 35;
    const int a = ab / 6, b = ab - a * 6;

    // ================= Phase 1: fold (one chunk per wave) ==================
    {
        float* dxw = lds + w * (CH * 8);            // 2 KB per wave
        const int chunk = blockIdx.x * 4 + w;       // < 1024
        const int j0 = chunk * CH;
        const int cnt = min(CH, NSEG - j0);         // 64 (63 for last chunk)
        for (int f = lane; f < CH * 8; f += 64) dxw[f] = 0.f;
        const float* xb = x + (size_t)j0 * DIM;
        for (int f = lane; f < cnt * DIM; f += 64) {
            int j = f / 6, k = f - j * 6;
            dxw[j * 8 + k] = xb[f + 6] - xb[f];
        }

        float ma[6], mb[6];
#pragma unroll
        for (int k = 0; k < 6; ++k) {
            ma[k] = (a == k) ? 1.f : 0.f;
            mb[k] = (b == k) ? 1.f : 0.f;
        }
        float r4[36], r3[6], r2 = 0.f, s1 = 0.f;
#pragma unroll
        for (int i = 0; i < 36; ++i) r4[i] = 0.f;
#pragma unroll
        for (int i = 0; i < 6; ++i) r3[i] = 0.f;

#pragma unroll 4
        for (int j = 0; j < CH; ++j) {
            const float4 q0 = *(const float4*)(dxw + j * 8);
            const float2 q1 = *(const float2*)(dxw + j * 8 + 4);
            const float dxv[6] = {q0.x, q0.y, q0.z, q0.w, q1.x, q1.y};
            float dxa = 0.f, dxb = 0.f;
#pragma unroll
            for (int k = 0; k < 6; ++k) {
                dxa = fmaf(ma[k], dxv[k], dxa);
                dxb = fmaf(mb[k], dxv[k], dxb);
            }
            float t2 = fmaf(dxb, fmaf(dxa, (1.f / 12.f), s1 * (1.f / 3.f)), r2);
            float t2h = 0.5f * t2;
            float wv[6];
#pragma unroll
            for (int cc = 0; cc < 6; ++cc) wv[cc] = fmaf(t2h, dxv[cc], r3[cc]);
#pragma unroll
            for (int cc = 0; cc < 6; ++cc)
#pragma unroll
                for (int d = 0; d < 6; ++d)
                    r4[cc * 6 + d] = fmaf(wv[cc], dxv[d], r4[cc * 6 + d]);
            float t3 = fmaf(dxa, (1.f / 3.f), s1);
            float v = fmaf(0.5f * t3, dxb, r2);
#pragma unroll
            for (int cc = 0; cc < 6; ++cc) r3[cc] = fmaf(v, dxv[cc], r3[cc]);
            r2 = fmaf(fmaf(0.5f, dxa, s1), dxb, r2);
            s1 += dxa;
        }

        if (lane < 36)
            acc_store_agent(ws0 + (size_t)chunk * PSTRIDE, ab, a, b, r4, r3, r2, s1);
    }
    __threadfence();
    grid.sync();
    __threadfence();

    // ======= Phases 2-4: staged radix-8 combines 1024 -> 128 -> 16 -> 2 ====
    {
        const float* src[3] = {ws0, ws1, ws2};
        float* dst[3] = {ws1, ws2, ws3};
        const int nblk[3] = {128, 16, 2};
#pragma unroll 1
        for (int ph = 0; ph < 3; ++ph) {
            if (blockIdx.x < (unsigned)nblk[ph]) {
                const float* gsrc = src[ph] + (size_t)blockIdx.x * 8 * PSTRIDE;
                for (int i = t; i < 8 * PSTRIDE; i += 256)
                    lds[i] = gload(gsrc + i);
                __syncthreads();
                if (w == 0) {
                    float r4[36], r3[6], r2, s1;
                    acc_load(lds, ab, a, r4, r3, r2, s1);
#pragma unroll 1
                    for (int r = 1; r < 8; ++r)
                        acc_chen(lds + r * PSTRIDE, ab, a, b, r4, r3, r2, s1);
                    if (lane < 36)
                        acc_store_agent(dst[ph] + (size_t)blockIdx.x * PSTRIDE,
                                        ab, a, b, r4, r3, r2, s1);
                }
            }
            __threadfence();
            grid.sync();
            __threadfence();
        }
    }

    // ================= Phase 5: 2 -> 1, flat output ========================
    if (blockIdx.x == 0) {
        for (int i = t; i < 2 * PSTRIDE; i += 256) lds[i] = gload(ws3 + i);
        __syncthreads();
        if (w == 0) {
            float r4[36], r3[6], r2, s1;
            acc_load(lds, ab, a, r4, r3, r2, s1);
            acc_chen(lds + PSTRIDE, ab, a, b, r4, r3, r2, s1);
            if (lane < 36) {
                float* O = out;           // flat 1554: L1@0 L2@6 L3@42 L4@258
                if (a == b) O[a] = s1;
                O[6 + ab] = r2;
                float* o3 = O + 42 + ab * 6;
#pragma unroll
                for (int i = 0; i < 3; ++i)
                    *(float2*)(o3 + 2 * i) = make_float2(r3[2 * i], r3[2 * i + 1]);
                float* o4 = O + 258 + ab * 36;    // 8B-aligned
#pragma unroll
                for (int i = 0; i < 18; ++i)
                    *(float2*)(o4 + 2 * i) = make_float2(r4[2 * i], r4[2 * i + 1]);
            }
        }
    }
}

// ---------------------------------------------------------------------------
extern "C" void kernel_launch(void* const* d_in, const int* in_sizes, int n_in,
                              void* d_out, int out_size, void* d_ws, size_t ws_size,
                              hipStream_t stream) {
    const float* x = (const float*)d_in[0];
    float* out = (float*)d_out;
    float* ws0 = (float*)d_ws;                          // 1024 padded partials
    float* ws1 = ws0 + (size_t)NCHUNK * PSTRIDE;        // 128
    float* ws2 = ws1 + (size_t)128 * PSTRIDE;           // 16
    float* ws3 = ws2 + (size_t)16 * PSTRIDE;            // 2

    void* args[6] = {(void*)&x, (void*)&out, (void*)&ws0,
                     (void*)&ws1, (void*)&ws2, (void*)&ws3};
    hipLaunchCooperativeKernel((void*)sig_all, dim3(256), dim3(256),
                               args, 0, stream);
}

// Round 9
// 123.821 us; speedup vs baseline: 3.1915x; 3.1915x over previous
//
#include <hip/hip_runtime.h>

#define DIM 6
#define NSEG 65535
#define CH 32            // segments per chunk
#define NCHUNK 2048      // NCHUNK*CH >= NSEG

// Padded partial-signature layout (per chunk), stride in floats.
// 16B-aligned sections: L1@0(6), L2@8(36), L3@48(216), L4@264(1296)
#define PSTRIDE 1568
#define PL1 0
#define PL2 8
#define PL3 48
#define PL4 264

// ---------------- Kernel 1: one wave per chunk, register-resident Chen fold -
// Lane ab=t (t<36, a=ab/6, b=ab%6) owns S4 row (36 regs), S3 row (6),
// S2[ab], private S1[a].  launch_bounds(64,2) -> <=256 VGPR: no spills.
__global__ __launch_bounds__(64, 2) void sig_fold(const float* __restrict__ x,
                                                  float* __restrict__ part) {
    __shared__ float dxs[CH * 8];   // dx row j at 8-float stride
    const int t = threadIdx.x;
    const int c = blockIdx.x;
    const int j0 = c * CH;
    const int cnt = min(CH, NSEG - j0);    // 32, or 31 for the last chunk

    for (int f = t; f < CH * 8; f += 64) dxs[f] = 0.f;
    __syncthreads();
    const float* xb = x + (size_t)j0 * DIM;
    for (int f = t; f < cnt * DIM; f += 64) {
        int j = f / 6, k = f - j * 6;
        dxs[j * 8 + k] = xb[f + 6] - xb[f];
    }
    __syncthreads();

    const int ab = (t < 36) ? t : 35;
    const int a = ab / 6, b = ab - a * 6;
    const float* dxap = dxs + a;    // lane-varying LDS bases (ds_read scalar)
    const float* dxbp = dxs + b;

    float r4[36], r3[6], r2 = 0.f, s1 = 0.f;
#pragma unroll
    for (int i = 0; i < 36; ++i) r4[i] = 0.f;
#pragma unroll
    for (int i = 0; i < 6; ++i) r3[i] = 0.f;

#pragma unroll 4
    for (int j = 0; j < CH; ++j) {
        const float4 q0 = *(const float4*)(dxs + j * 8);
        const float2 q1 = *(const float2*)(dxs + j * 8 + 4);
        const float dxv[6] = {q0.x, q0.y, q0.z, q0.w, q1.x, q1.y}; // const-idx only
        const float dxa = dxap[j * 8];
        const float dxb = dxbp[j * 8];

        // t2 = S2 + dx_b*(S1/3 + dx_a/12)            (old S2, S1)
        float t2 = fmaf(dxb, fmaf(dxa, (1.f / 12.f), s1 * (1.f / 3.f)), r2);
        float t2h = 0.5f * t2;
        // S4[cd] += (S3[c] + t2*0.5*dx[c]) * dx[d]   (old S3)
        float w[6];
#pragma unroll
        for (int cc = 0; cc < 6; ++cc) w[cc] = fmaf(t2h, dxv[cc], r3[cc]);
#pragma unroll
        for (int cc = 0; cc < 6; ++cc)
#pragma unroll
            for (int d = 0; d < 6; ++d)
                r4[cc * 6 + d] = fmaf(w[cc], dxv[d], r4[cc * 6 + d]);
        // S3[c] += (S2 + t3*0.5*dx_b) * dx[c],  t3 = S1 + dx_a/3
        float t3 = fmaf(dxa, (1.f / 3.f), s1);
        float v = fmaf(0.5f * t3, dxb, r2);
#pragma unroll
        for (int cc = 0; cc < 6; ++cc) r3[cc] = fmaf(v, dxv[cc], r3[cc]);
        // S2 += (S1 + 0.5*dx_a) * dx_b ; S1 += dx_a
        r2 = fmaf(fmaf(0.5f, dxa, s1), dxb, r2);
        s1 += dxa;
    }

    if (t < 36) {
        float* P = part + (size_t)c * PSTRIDE;
        if (a == b) P[PL1 + a] = s1;
        P[PL2 + ab] = r2;
        float* p3 = P + PL3 + ab * 6;
        *(float2*)(p3 + 0) = make_float2(r3[0], r3[1]);
        *(float2*)(p3 + 2) = make_float2(r3[2], r3[3]);
        *(float2*)(p3 + 4) = make_float2(r3[4], r3[5]);
        float* p4 = P + PL4 + ab * 36;
#pragma unroll
        for (int i = 0; i < 9; ++i)
            *(float4*)(p4 + 4 * i) =
                make_float4(r4[4 * i], r4[4 * i + 1], r4[4 * i + 2], r4[4 * i + 3]);
    }
}

// ---- register-resident Chen accumulate, LDS-fed, LOW register pressure -----
// Streams B2/B3row-b/B4 quad-by-quad inside the T4 loop: peak live ~70 floats.
__device__ __forceinline__ void acc_chen(const float* __restrict__ Us,
                                         int ab, int a, int b,
                                         float* r4, float* r3,
                                         float& r2, float& s1) {
    float b1[6];
#pragma unroll
    for (int d = 0; d < 6; ++d) b1[d] = Us[PL1 + d];
    float b1a = Us[PL1 + a];
    float b1b = Us[PL1 + b];
    float b2ab = Us[PL2 + ab];
    float b2rb[6];
    {
        const float* p = Us + PL2 + b * 6;
#pragma unroll
        for (int i = 0; i < 3; ++i) {
            float2 q = *(const float2*)(p + 2 * i);
            b2rb[2 * i] = q.x; b2rb[2 * i + 1] = q.y;
        }
    }
    float b3ab[6];
    {
        const float* p = Us + PL3 + ab * 6;
#pragma unroll
        for (int i = 0; i < 3; ++i) {
            float2 q = *(const float2*)(p + 2 * i);
            b3ab[2 * i] = q.x; b3ab[2 * i + 1] = q.y;
        }
    }
    // T4: stream b2 (uniform), b3 row b, b4 row ab as float4 quads
    const float* p2 = Us + PL2;
    const float* p3b = Us + PL3 + b * 36;
    const float* p4 = Us + PL4 + ab * 36;
#pragma unroll
    for (int i = 0; i < 9; ++i) {
        float4 q2 = *(const float4*)(p2 + 4 * i);
        float4 q3 = *(const float4*)(p3b + 4 * i);
        float4 q4 = *(const float4*)(p4 + 4 * i);
        const float v2[4] = {q2.x, q2.y, q2.z, q2.w};
        const float v3[4] = {q3.x, q3.y, q3.z, q3.w};
        const float v4[4] = {q4.x, q4.y, q4.z, q4.w};
#pragma unroll
        for (int k = 0; k < 4; ++k) {
            const int cd = 4 * i + k, cc = cd / 6, d = cd - cc * 6;
            float v = r4[cd] + v4[k];
            v = fmaf(r3[cc], b1[d], v);
            v = fmaf(r2, v2[k], v);
            r4[cd] = fmaf(s1, v3[k], v);
        }
    }
    // T3 (old r2, s1)
#pragma unroll
    for (int cc = 0; cc < 6; ++cc) {
        float v = r3[cc] + b3ab[cc];
        v = fmaf(r2, b1[cc], v);
        r3[cc] = fmaf(s1, b2rb[cc], v);
    }
    // T2, T1 (old s1)
    r2 = fmaf(s1, b1b, r2 + b2ab);
    s1 += b1a;
}

__device__ __forceinline__ void acc_load(const float* __restrict__ P,
                                         int ab, int a,
                                         float* r4, float* r3,
                                         float& r2, float& s1) {
    s1 = P[PL1 + a];
    r2 = P[PL2 + ab];
    const float* p3 = P + PL3 + ab * 6;
#pragma unroll
    for (int i = 0; i < 3; ++i) {
        float2 q = *(const float2*)(p3 + 2 * i);
        r3[2 * i] = q.x; r3[2 * i + 1] = q.y;
    }
    const float* p4 = P + PL4 + ab * 36;
#pragma unroll
    for (int i = 0; i < 9; ++i) {
        float4 q = *(const float4*)(p4 + 4 * i);
        r4[4 * i] = q.x; r4[4 * i + 1] = q.y;
        r4[4 * i + 2] = q.z; r4[4 * i + 3] = q.w;
    }
}

// ---------------- Kernel 2: LDS-staged radix-R Chen combine (R <= 8) --------
__global__ __launch_bounds__(64, 1) void sig_comb(const float* __restrict__ in,
                                                  float* __restrict__ out,
                                                  int R, int flat_out) {
    __shared__ __align__(16) float U[8 * PSTRIDE];   // 50.2 KB
    const int t = threadIdx.x;
    const int ab = (t < 36) ? t : 35;
    const int a = ab / 6, b = ab - a * 6;

    {   // coalesced staging (parallel float4 loads; one latency)
        const float4* g4 = (const float4*)(in + (size_t)blockIdx.x * R * PSTRIDE);
        float4* s4 = (float4*)U;
        const int nf4 = R * (PSTRIDE / 4);
        for (int i = t; i < nf4; i += 64) s4[i] = g4[i];
    }
    __syncthreads();

    float r4[36], r3[6], r2, s1;
    acc_load(U, ab, a, r4, r3, r2, s1);
#pragma unroll 1
    for (int r = 1; r < R; ++r)
        acc_chen(U + r * PSTRIDE, ab, a, b, r4, r3, r2, s1);

    if (t < 36) {
        if (flat_out) {
            float* O = out;               // flat 1554: L1@0 L2@6 L3@42 L4@258
            if (a == b) O[a] = s1;
            O[6 + ab] = r2;
            float* o3 = O + 42 + ab * 6;
#pragma unroll
            for (int i = 0; i < 3; ++i)
                *(float2*)(o3 + 2 * i) = make_float2(r3[2 * i], r3[2 * i + 1]);
            float* o4 = O + 258 + ab * 36;    // 8B-aligned
#pragma unroll
            for (int i = 0; i < 18; ++i)
                *(float2*)(o4 + 2 * i) = make_float2(r4[2 * i], r4[2 * i + 1]);
        } else {
            float* P = out + (size_t)blockIdx.x * PSTRIDE;
            if (a == b) P[PL1 + a] = s1;
            P[PL2 + ab] = r2;
            float* p3 = P + PL3 + ab * 6;
#pragma unroll
            for (int i = 0; i < 3; ++i)
                *(float2*)(p3 + 2 * i) = make_float2(r3[2 * i], r3[2 * i + 1]);
            float* p4 = P + PL4 + ab * 36;
#pragma unroll
            for (int i = 0; i < 9; ++i)
                *(float4*)(p4 + 4 * i) =
                    make_float4(r4[4 * i], r4[4 * i + 1], r4[4 * i + 2], r4[4 * i + 3]);
        }
    }
}

// ---------------------------------------------------------------------------
extern "C" void kernel_launch(void* const* d_in, const int* in_sizes, int n_in,
                              void* d_out, int out_size, void* d_ws, size_t ws_size,
                              hipStream_t stream) {
    const float* x = (const float*)d_in[0];
    float* out = (float*)d_out;
    float* ws0 = (float*)d_ws;                          // 2048 padded partials
    float* ws1 = ws0 + (size_t)NCHUNK * PSTRIDE;        // 256
    float* ws2 = ws1 + (size_t)256 * PSTRIDE;           // 32
    float* ws3 = ws2 + (size_t)32 * PSTRIDE;            // 4

    sig_fold<<<NCHUNK, 64, 0, stream>>>(x, ws0);
    sig_comb<<<256, 64, 0, stream>>>(ws0, ws1, 8, 0);   // 2048 -> 256
    sig_comb<<<32, 64, 0, stream>>>(ws1, ws2, 8, 0);    // 256  -> 32
    sig_comb<<<4, 64, 0, stream>>>(ws2, ws3, 8, 0);     // 32   -> 4
    sig_comb<<<1, 64, 0, stream>>>(ws3, out, 4, 1);     // 4    -> 1
}